// Round 10
// baseline (196.621 us; speedup 1.0000x reference)
//
#include <hip/hip_runtime.h>
#include <math.h>

#define BATCH 64
#define NV 1024
#define NL 512
#define DIM 512
#define TMM 256
#define TNN 256
#define BK 32
#define NKT (DIM / BK)   // 16 K-iterations

typedef __bf16 bf16x8 __attribute__((ext_vector_type(8)));
typedef __bf16 bf16x4 __attribute__((ext_vector_type(4)));
typedef float f32x4 __attribute__((ext_vector_type(4)));

// =====================================================================
// Fused kernel: fp32 load -> (norms, bf16 convert) -> LDS -> MFMA GEMM
// -> distance epilogue -> row/col min partials.
// R10: 1024 threads = 16 waves as 4x4 of 64x64 wave-tiles -> 256x256
// block tile. Cache-read traffic per grid: NL/TNN*video + NV/TMM*lang
// = 2x134 + 4x67 = 536 MB (was 804 MB at 256x128) — the R9 evidence
// says we are L3-read-BW-bound, so time should scale with traffic.
//
// Register envelope (R4/R6/R8): per-wave acc[4][4] = 64 AGPR + ~60
// arch VGPR = 128 unified -> 4 waves/SIMD -> exactly one 16-wave
// block/CU. Plain __launch_bounds__(1024) (no min-waves arg) makes the
// allocator honor launchability without over-tightening (R6 lesson).
// Staging loads issued and consumed in the same iteration (R7 lesson).
// Lane remap keeps ds_write bank-even (R8/R9: conflicts == 0).
// =====================================================================
__global__ __launch_bounds__(1024) void fused_distmin_kernel(
    const float* __restrict__ video, const float* __restrict__ lang,
    float* __restrict__ rowpart, float* __restrict__ colpart) {
    // Octet-major LDS: slab o in [0,4) holds k = [o*8, o*8+8) for all rows,
    // 16B per (o,row) entry. b128 frag reads and b64 writes bank-even.
    __shared__ __align__(16) ushort AsU[2][4][TMM][8];  // 32 KB
    __shared__ __align__(16) ushort BsU[2][4][TNN][8];  // 32 KB
    __shared__ float anrm[TMM], bnrm[TNN];              // 2 KB
    // Epilogue scratch aliased onto AsU (dead after last MFMA + barrier).
    float* rowred = (float*)AsU;             // [4][TMM] = 4 KB
    float* colred = (float*)AsU + 4 * TMM;   // [4][TNN] = 4 KB

    // XCD-aware swizzle: nwg = 512 = 8 XCD * 64; each XCD gets 8 whole
    // batches (8 blocks/batch).
    const int wg = ((blockIdx.x & 7) << 6) | (blockIdx.x >> 3);
    const int b = wg >> 3;          // 64 batches
    const int mt = (wg >> 1) & 3;   // 4 video row-blocks of 256
    const int nt = wg & 1;          // 2 lang col-blocks of 256

    const int tid = threadIdx.x;
    const int lane = tid & 63;
    const int w = tid >> 6;         // 0..15
    const int wrow = w >> 2;        // 0..3
    const int wcol = w & 3;         // 0..3
    const int lr = lane & 15;
    const int g = lane >> 4;        // k-octet for fragment reads

    // staging geometry (bank-even lane remap):
    const int half = tid & 1;            // 8B half of the 16B entry
    const int o_sl = (tid >> 4) & 3;     // LDS slab / k-octet
    const int srow = ((tid >> 6) << 3) + ((tid >> 1) & 7);  // 0..127
    const int skq = o_sl * 2 + half;     // k-quad in [0,8)

    const float* Ath = video + ((size_t)b * NV + (size_t)mt * TMM + srow) * DIM + skq * 4;
    const float* Bth = lang + ((size_t)b * NL + (size_t)nt * TNN + srow) * DIM + skq * 4;

    float nA[2] = {0.f, 0.f};   // rows srow, srow+128
    float nB[2] = {0.f, 0.f};

    f32x4 acc[4][4];
#pragma unroll
    for (int i = 0; i < 4; i++)
#pragma unroll
        for (int j = 0; j < 4; j++) acc[i][j] = (f32x4){0.f, 0.f, 0.f, 0.f};

    float4 va[2], vb[2];

    auto load_chunk = [&](int k0) {
#pragma unroll
        for (int t = 0; t < 2; ++t) {
            va[t] = *(const float4*)(Ath + (size_t)t * 128 * DIM + k0);
            vb[t] = *(const float4*)(Bth + (size_t)t * 128 * DIM + k0);
        }
    };
    auto write_chunk = [&](int buf) {
#pragma unroll
        for (int t = 0; t < 2; ++t) {
            float4 v = va[t];
            nA[t] += v.x * v.x + v.y * v.y + v.z * v.z + v.w * v.w;
            bf16x4 p = {(__bf16)v.x, (__bf16)v.y, (__bf16)v.z, (__bf16)v.w};
            *(bf16x4*)&AsU[buf][o_sl][srow + 128 * t][half * 4] = p;
            float4 u = vb[t];
            nB[t] += u.x * u.x + u.y * u.y + u.z * u.z + u.w * u.w;
            bf16x4 q = {(__bf16)u.x, (__bf16)u.y, (__bf16)u.z, (__bf16)u.w};
            *(bf16x4*)&BsU[buf][o_sl][srow + 128 * t][half * 4] = q;
        }
    };

    // prologue: stage k-tile 0 into buf 0
    load_chunk(0);
    write_chunk(0);
    __syncthreads();

    // R7-proven cadence: loads issued at iter top, consumed (write) after
    // MFMA in the SAME iteration -> no load live across the barrier.
    for (int kt = 0; kt < NKT; ++kt) {
        const int cur = kt & 1;
        const bool more = (kt + 1) < NKT;
        if (more) load_chunk((kt + 1) * BK);

        bf16x8 av[4], bv[4];
#pragma unroll
        for (int fr = 0; fr < 4; ++fr)
            av[fr] = *(const bf16x8*)&AsU[cur][g][wrow * 64 + fr * 16 + lr][0];
#pragma unroll
        for (int fc = 0; fc < 4; ++fc)
            bv[fc] = *(const bf16x8*)&BsU[cur][g][wcol * 64 + fc * 16 + lr][0];
#pragma unroll
        for (int fr = 0; fr < 4; ++fr)
#pragma unroll
            for (int fc = 0; fc < 4; ++fc)
                acc[fr][fc] = __builtin_amdgcn_mfma_f32_16x16x32_bf16(
                    av[fr], bv[fc], acc[fr][fc], 0, 0, 0);

        if (more) write_chunk(cur ^ 1);   // cvt + norm-fma + ds_write after MFMA
        __syncthreads();
    }

    // ---- norms: reduce partials across the 8 threads sharing each row ----
    // (row-sharing threads differ in tid bits {0,4,5} under the remap)
#pragma unroll
    for (int si = 0; si < 3; ++si) {
        const int s = (si == 0) ? 1 : (si == 1) ? 16 : 32;
#pragma unroll
        for (int t = 0; t < 2; ++t) {
            nA[t] += __shfl_xor(nA[t], s);
            nB[t] += __shfl_xor(nB[t], s);
        }
    }
    if ((tid & 49) == 0) {   // bits 0,4,5 zero -> one writer per row
#pragma unroll
        for (int t = 0; t < 2; ++t) {
            anrm[srow + 128 * t] = nA[t];
            bnrm[srow + 128 * t] = nB[t];
        }
    }
    __syncthreads();   // after this barrier AsU is dead -> rowred/colred alias OK

    // ---- epilogue: d = |v|^2 - 2 dot + |l|^2, row/col mins ----
    const int rgrp = (lane >> 4) * 4;
    float anorm[4][4];
#pragma unroll
    for (int fr = 0; fr < 4; ++fr)
#pragma unroll
        for (int r = 0; r < 4; ++r)
            anorm[fr][r] = anrm[wrow * 64 + fr * 16 + rgrp + r];
    float bnorm[4];
#pragma unroll
    for (int fc = 0; fc < 4; ++fc)
        bnorm[fc] = bnrm[wcol * 64 + fc * 16 + lr];

    float rmin[4][4];
    float cmin[4];
#pragma unroll
    for (int fr = 0; fr < 4; ++fr)
#pragma unroll
        for (int r = 0; r < 4; ++r) rmin[fr][r] = INFINITY;
#pragma unroll
    for (int fc = 0; fc < 4; ++fc) cmin[fc] = INFINITY;

#pragma unroll
    for (int fr = 0; fr < 4; ++fr)
#pragma unroll
        for (int fc = 0; fc < 4; ++fc)
#pragma unroll
            for (int r = 0; r < 4; ++r) {
                float d = anorm[fr][r] - 2.0f * acc[fr][fc][r] + bnorm[fc];
                rmin[fr][r] = fminf(rmin[fr][r], d);
                cmin[fc] = fminf(cmin[fc], d);
            }

    // row-min across the 16 lanes holding a fragment's 16 cols
#pragma unroll
    for (int fr = 0; fr < 4; ++fr)
#pragma unroll
        for (int r = 0; r < 4; ++r) {
#pragma unroll
            for (int off = 1; off < 16; off <<= 1)
                rmin[fr][r] = fminf(rmin[fr][r], __shfl_xor(rmin[fr][r], off));
        }
    // col-min across the 4 row-groups (lane>>4)
#pragma unroll
    for (int fc = 0; fc < 4; ++fc) {
#pragma unroll
        for (int off = 16; off < 64; off <<= 1)
            cmin[fc] = fminf(cmin[fc], __shfl_xor(cmin[fc], off));
    }

    if ((lane & 15) == 0) {
#pragma unroll
        for (int fr = 0; fr < 4; ++fr)
#pragma unroll
            for (int r = 0; r < 4; ++r)
                rowred[wcol * TMM + wrow * 64 + fr * 16 + rgrp + r] = rmin[fr][r];
    }
    if (lane < 16) {
#pragma unroll
        for (int fc = 0; fc < 4; ++fc)
            colred[wrow * TNN + wcol * 64 + fc * 16 + lane] = cmin[fc];
    }
    __syncthreads();
    if (tid < TMM) {
        float m = INFINITY;
#pragma unroll
        for (int k = 0; k < 4; ++k) m = fminf(m, rowred[k * TMM + tid]);
        rowpart[((size_t)(b * 2 + nt)) * NV + mt * TMM + tid] = m;
    } else if (tid < TMM + TNN) {
        int c2 = tid - TMM;
        float m = INFINITY;
#pragma unroll
        for (int k = 0; k < 4; ++k) m = fminf(m, colred[k * TNN + c2]);
        colpart[((size_t)(b * 4 + mt)) * NL + nt * TNN + c2] = m;
    }
}

// ---------------- final reduce ----------------------------------------------
__global__ __launch_bounds__(256) void reduce2_kernel(
    const float* __restrict__ rowpart, const float* __restrict__ colpart,
    float* __restrict__ out) {
    int b = blockIdx.x;
    int tid = threadIdx.x;
    float s = 0.0f;
    for (int r = tid; r < NV; r += 256) {
        float m = fminf(rowpart[((size_t)(b * 2 + 0)) * NV + r],
                        rowpart[((size_t)(b * 2 + 1)) * NV + r]);
        s += m * (1.0f / NV);
    }
    for (int c = tid; c < NL; c += 256) {
        float m = INFINITY;
#pragma unroll
        for (int mt = 0; mt < 4; mt++)
            m = fminf(m, colpart[((size_t)(b * 4 + mt)) * NL + c]);
        s += m * (1.0f / NL);
    }
    __shared__ float red[4];
#pragma unroll
    for (int off = 32; off > 0; off >>= 1) s += __shfl_down(s, off);
    if ((tid & 63) == 0) red[tid >> 6] = s;
    __syncthreads();
    if (tid == 0) out[b] = red[0] + red[1] + red[2] + red[3];
}

// ============================================================================
extern "C" void kernel_launch(void* const* d_in, const int* in_sizes, int n_in,
                              void* d_out, int out_size, void* d_ws, size_t ws_size,
                              hipStream_t stream) {
    const float* video = (const float*)d_in[0];  // [64,1024,512] fp32
    const float* lang = (const float*)d_in[1];   // [64,512,512] fp32
    float* out = (float*)d_out;                  // [64]

    float* rowpart = (float*)d_ws;                      // 64*2*1024 floats (0.5 MB)
    float* colpart = rowpart + (size_t)BATCH * 2 * NV;  // 64*4*512 floats (0.5 MB)

    fused_distmin_kernel<<<dim3(512), 1024, 0, stream>>>(video, lang, rowpart, colpart);
    reduce2_kernel<<<BATCH, 256, 0, stream>>>(rowpart, colpart, out);
}

// Round 11
// 66.512 us; speedup vs baseline: 2.9562x; 2.9562x over previous
//
#include <hip/hip_runtime.h>
#include <math.h>

#define BATCH 64
#define NV 1024
#define NL 512
#define DIM 512
#define TMM 256
#define TNN 256
#define BK 32
#define NKT (DIM / BK)   // 16 K-iterations

typedef __bf16 bf16x8 __attribute__((ext_vector_type(8)));
typedef __bf16 bf16x4 __attribute__((ext_vector_type(4)));
typedef float f32x4 __attribute__((ext_vector_type(4)));

// =====================================================================
// Fused kernel: fp32 load -> (norms, bf16 convert) -> LDS -> MFMA GEMM
// -> distance epilogue -> row/col min partials.
// R11: 256x256 tile with 512 threads = 8 waves as 4x2 of 64x128
// wave-tiles (acc[4][8] = 128 regs/wave). Cache-read traffic per grid:
// 2x video + 4x lang = 536 MB (was 804 at 256x128) — R9 evidence says
// the kernel is cache-read-BW + staging-work bound, both scale with
// traffic.
//
// Register spelling (R4/R6/R8/R10 lessons): __launch_bounds__(512,2)
// is the ONLY proven-safe form — R10's bare (1024) let the backend cap
// regs at 64 and spill the accumulator (420 MB scratch). (512,2) caps
// at 256 regs/wave; natural usage ~210 -> no spill, 2 waves/SIMD,
// 1 block/CU. Loads issued+consumed in the same iteration (R7).
// Bank-even lane remap (R8/R9: SQ_LDS_BANK_CONFLICT == 0) unchanged.
// =====================================================================
__global__ __launch_bounds__(512, 2) void fused_distmin_kernel(
    const float* __restrict__ video, const float* __restrict__ lang,
    float* __restrict__ rowpart, float* __restrict__ colpart) {
    // Octet-major LDS: slab o in [0,4) holds k = [o*8, o*8+8) for all rows,
    // 16B per (o,row) entry. b128 frag reads and b64 writes bank-even.
    __shared__ __align__(16) ushort AsU[2][4][TMM][8];  // 32 KB
    __shared__ __align__(16) ushort BsU[2][4][TNN][8];  // 32 KB
    __shared__ float anrm[TMM], bnrm[TNN];              // 2 KB
    // Epilogue scratch aliased onto AsU (dead after last MFMA + barrier).
    float* rowred = (float*)AsU;             // [2][TMM] = 2 KB
    float* colred = (float*)AsU + 2 * TMM;   // [4][TNN] = 4 KB

    // XCD-aware swizzle: nwg = 512 = 8 XCD * 64; each XCD gets 8 whole
    // batches (8 blocks/batch).
    const int wg = ((blockIdx.x & 7) << 6) | (blockIdx.x >> 3);
    const int b = wg >> 3;          // 64 batches
    const int mt = (wg >> 1) & 3;   // 4 video row-blocks of 256
    const int nt = wg & 1;          // 2 lang col-blocks of 256

    const int tid = threadIdx.x;
    const int lane = tid & 63;
    const int w = tid >> 6;         // 0..7
    const int wrow = w >> 1;        // 0..3  (64-row band)
    const int wcol = w & 1;         // 0..1  (128-col band)
    const int lr = lane & 15;
    const int g = lane >> 4;        // k-octet for fragment reads

    // staging geometry (bank-even lane remap, R8-proven):
    const int half = tid & 1;            // 8B half of the 16B entry
    const int o_sl = (tid >> 4) & 3;     // LDS slab / k-octet
    const int srow = ((tid >> 6) << 3) + ((tid >> 1) & 7);  // 0..63
    const int skq = o_sl * 2 + half;     // k-quad in [0,8)

    const float* Ath = video + ((size_t)b * NV + (size_t)mt * TMM + srow) * DIM + skq * 4;
    const float* Bth = lang + ((size_t)b * NL + (size_t)nt * TNN + srow) * DIM + skq * 4;

    float nA[4] = {0.f, 0.f, 0.f, 0.f};   // rows srow + 64t
    float nB[4] = {0.f, 0.f, 0.f, 0.f};

    f32x4 acc[4][8];
#pragma unroll
    for (int i = 0; i < 4; i++)
#pragma unroll
        for (int j = 0; j < 8; j++) acc[i][j] = (f32x4){0.f, 0.f, 0.f, 0.f};

    float4 va[4], vb[4];

    auto load_chunk = [&](int k0) {
#pragma unroll
        for (int t = 0; t < 4; ++t) {
            va[t] = *(const float4*)(Ath + (size_t)t * 64 * DIM + k0);
            vb[t] = *(const float4*)(Bth + (size_t)t * 64 * DIM + k0);
        }
    };
    auto write_chunk = [&](int buf) {
#pragma unroll
        for (int t = 0; t < 4; ++t) {
            float4 v = va[t];
            nA[t] += v.x * v.x + v.y * v.y + v.z * v.z + v.w * v.w;
            bf16x4 p = {(__bf16)v.x, (__bf16)v.y, (__bf16)v.z, (__bf16)v.w};
            *(bf16x4*)&AsU[buf][o_sl][srow + 64 * t][half * 4] = p;
            float4 u = vb[t];
            nB[t] += u.x * u.x + u.y * u.y + u.z * u.z + u.w * u.w;
            bf16x4 q = {(__bf16)u.x, (__bf16)u.y, (__bf16)u.z, (__bf16)u.w};
            *(bf16x4*)&BsU[buf][o_sl][srow + 64 * t][half * 4] = q;
        }
    };

    // prologue: stage k-tile 0 into buf 0
    load_chunk(0);
    write_chunk(0);
    __syncthreads();

    // R7-proven cadence: loads issued at iter top, consumed (write) after
    // MFMA in the SAME iteration -> no load live across the barrier.
    for (int kt = 0; kt < NKT; ++kt) {
        const int cur = kt & 1;
        const bool more = (kt + 1) < NKT;
        if (more) load_chunk((kt + 1) * BK);

        bf16x8 av[4], bv[8];
#pragma unroll
        for (int fr = 0; fr < 4; ++fr)
            av[fr] = *(const bf16x8*)&AsU[cur][g][wrow * 64 + fr * 16 + lr][0];
#pragma unroll
        for (int fc = 0; fc < 8; ++fc)
            bv[fc] = *(const bf16x8*)&BsU[cur][g][wcol * 128 + fc * 16 + lr][0];
#pragma unroll
        for (int fr = 0; fr < 4; ++fr)
#pragma unroll
            for (int fc = 0; fc < 8; ++fc)
                acc[fr][fc] = __builtin_amdgcn_mfma_f32_16x16x32_bf16(
                    av[fr], bv[fc], acc[fr][fc], 0, 0, 0);

        if (more) write_chunk(cur ^ 1);   // cvt + norm-fma + ds_write after MFMA
        __syncthreads();
    }

    // ---- norms: reduce partials across the 8 threads sharing each row ----
    // (row-sharing threads differ in tid bits {0,4,5} under the remap)
#pragma unroll
    for (int si = 0; si < 3; ++si) {
        const int s = (si == 0) ? 1 : (si == 1) ? 16 : 32;
#pragma unroll
        for (int t = 0; t < 4; ++t) {
            nA[t] += __shfl_xor(nA[t], s);
            nB[t] += __shfl_xor(nB[t], s);
        }
    }
    if ((tid & 49) == 0) {   // bits 0,4,5 zero -> one writer per row
#pragma unroll
        for (int t = 0; t < 4; ++t) {
            anrm[srow + 64 * t] = nA[t];
            bnrm[srow + 64 * t] = nB[t];
        }
    }
    __syncthreads();   // after this barrier AsU is dead -> rowred/colred alias OK

    // ---- epilogue: d = |v|^2 - 2 dot + |l|^2, row/col mins ----
    const int rgrp = (lane >> 4) * 4;
    float anorm[4][4];
#pragma unroll
    for (int fr = 0; fr < 4; ++fr)
#pragma unroll
        for (int r = 0; r < 4; ++r)
            anorm[fr][r] = anrm[wrow * 64 + fr * 16 + rgrp + r];
    float bnorm[8];
#pragma unroll
    for (int fc = 0; fc < 8; ++fc)
        bnorm[fc] = bnrm[wcol * 128 + fc * 16 + lr];

    float rmin[4][4];
    float cmin[8];
#pragma unroll
    for (int fr = 0; fr < 4; ++fr)
#pragma unroll
        for (int r = 0; r < 4; ++r) rmin[fr][r] = INFINITY;
#pragma unroll
    for (int fc = 0; fc < 8; ++fc) cmin[fc] = INFINITY;

#pragma unroll
    for (int fr = 0; fr < 4; ++fr)
#pragma unroll
        for (int fc = 0; fc < 8; ++fc)
#pragma unroll
            for (int r = 0; r < 4; ++r) {
                float d = anorm[fr][r] - 2.0f * acc[fr][fc][r] + bnorm[fc];
                rmin[fr][r] = fminf(rmin[fr][r], d);
                cmin[fc] = fminf(cmin[fc], d);
            }

    // row-min across the 16 lanes holding a fragment's 16 cols
#pragma unroll
    for (int fr = 0; fr < 4; ++fr)
#pragma unroll
        for (int r = 0; r < 4; ++r) {
#pragma unroll
            for (int off = 1; off < 16; off <<= 1)
                rmin[fr][r] = fminf(rmin[fr][r], __shfl_xor(rmin[fr][r], off));
        }
    // col-min across the 4 row-groups (lane>>4)
#pragma unroll
    for (int fc = 0; fc < 8; ++fc) {
#pragma unroll
        for (int off = 16; off < 64; off <<= 1)
            cmin[fc] = fminf(cmin[fc], __shfl_xor(cmin[fc], off));
    }

    if ((lane & 15) == 0) {
#pragma unroll
        for (int fr = 0; fr < 4; ++fr)
#pragma unroll
            for (int r = 0; r < 4; ++r)
                rowred[wcol * TMM + wrow * 64 + fr * 16 + rgrp + r] = rmin[fr][r];
    }
    if (lane < 16) {
#pragma unroll
        for (int fc = 0; fc < 8; ++fc)
            colred[wrow * TNN + wcol * 128 + fc * 16 + lane] = cmin[fc];
    }
    __syncthreads();
    if (tid < TMM) {
        rowpart[((size_t)(b * 2 + nt)) * NV + mt * TMM + tid] =
            fminf(rowred[tid], rowred[TMM + tid]);
    } else {
        int c2 = tid - TMM;
        float m = INFINITY;
#pragma unroll
        for (int k = 0; k < 4; ++k) m = fminf(m, colred[k * TNN + c2]);
        colpart[((size_t)(b * 4 + mt)) * NL + nt * TNN + c2] = m;
    }
}

// ---------------- final reduce ----------------------------------------------
__global__ __launch_bounds__(256) void reduce2_kernel(
    const float* __restrict__ rowpart, const float* __restrict__ colpart,
    float* __restrict__ out) {
    int b = blockIdx.x;
    int tid = threadIdx.x;
    float s = 0.0f;
    for (int r = tid; r < NV; r += 256) {
        float m = fminf(rowpart[((size_t)(b * 2 + 0)) * NV + r],
                        rowpart[((size_t)(b * 2 + 1)) * NV + r]);
        s += m * (1.0f / NV);
    }
    for (int c = tid; c < NL; c += 256) {
        float m = INFINITY;
#pragma unroll
        for (int mt = 0; mt < 4; mt++)
            m = fminf(m, colpart[((size_t)(b * 4 + mt)) * NL + c]);
        s += m * (1.0f / NL);
    }
    __shared__ float red[4];
#pragma unroll
    for (int off = 32; off > 0; off >>= 1) s += __shfl_down(s, off);
    if ((tid & 63) == 0) red[tid >> 6] = s;
    __syncthreads();
    if (tid == 0) out[b] = red[0] + red[1] + red[2] + red[3];
}

// ============================================================================
extern "C" void kernel_launch(void* const* d_in, const int* in_sizes, int n_in,
                              void* d_out, int out_size, void* d_ws, size_t ws_size,
                              hipStream_t stream) {
    const float* video = (const float*)d_in[0];  // [64,1024,512] fp32
    const float* lang = (const float*)d_in[1];   // [64,512,512] fp32
    float* out = (float*)d_out;                  // [64]

    float* rowpart = (float*)d_ws;                      // 64*2*1024 floats (0.5 MB)
    float* colpart = rowpart + (size_t)BATCH * 2 * NV;  // 64*4*512 floats (0.5 MB)

    fused_distmin_kernel<<<dim3(512), 512, 0, stream>>>(video, lang, rowpart, colpart);
    reduce2_kernel<<<BATCH, 256, 0, stream>>>(rowpart, colpart, out);
}